// Round 6
// baseline (668.732 us; speedup 1.0000x reference)
//
#include <hip/hip_runtime.h>
#include <cstdint>
#include <cstddef>

#define B_  8
#define C_  256
#define HW_ 16384
#define K_  64
#define PPB 1024          // pixels per scatter block
#define NPB (HW_ / PPB)   // 16 scatter blocks per batch

typedef __attribute__((ext_vector_type(8))) short bf16x8;
typedef __attribute__((ext_vector_type(4))) float f32x4;

__device__ __forceinline__ unsigned f2bf(float f) {
    unsigned u = __builtin_bit_cast(unsigned, f);
    return (u + 0x7FFFu + ((u >> 16) & 1u)) >> 16;
}
__device__ __forceinline__ float bf2f(unsigned h) {
    unsigned u = h << 16;
    return __builtin_bit_cast(float, u);
}

// ---------------- K1: segment scatter-sum -> per-block partials ----------
// grid (16, 8): 1024 pixels per block. lane = pixel (4 px per thread via
// float4), cluster ids in registers; coalesced 1KB/wave-instr global reads;
// fire-and-forget ds_add_f32 into lsum[k*257+c] -> bank (k+c)%32, ~2-way.
__global__ __launch_bounds__(256) void k_scatter(const float* __restrict__ x,
                                                 const int* __restrict__ idx,
                                                 float* __restrict__ part,
                                                 float* __restrict__ pcnt) {
    __shared__ float lsum[K_ * 257];   // 65.8 KB
    __shared__ float lcnt[K_];
    const int tid = threadIdx.x;
    const int b = blockIdx.y;
    const int pb = blockIdx.x;
    const int p0 = pb * PPB;

    for (int i = tid; i < K_ * 257; i += 256) lsum[i] = 0.f;
    if (tid < K_) lcnt[tid] = 0.f;
    __syncthreads();

    const int p = p0 + tid * 4;
    const int4 kv = *(const int4*)(idx + b * HW_ + p);
    atomicAdd(&lcnt[kv.x], 1.f);
    atomicAdd(&lcnt[kv.y], 1.f);
    atomicAdd(&lcnt[kv.z], 1.f);
    atomicAdd(&lcnt[kv.w], 1.f);

    float* a0 = &lsum[kv.x * 257];
    float* a1 = &lsum[kv.y * 257];
    float* a2 = &lsum[kv.z * 257];
    float* a3 = &lsum[kv.w * 257];
    const float* xp = x + (size_t)b * C_ * HW_ + p;
    #pragma unroll 8
    for (int c = 0; c < C_; ++c) {
        float4 v = *(const float4*)(xp + (size_t)c * HW_);
        atomicAdd(a0 + c, v.x);
        atomicAdd(a1 + c, v.y);
        atomicAdd(a2 + c, v.z);
        atomicAdd(a3 + c, v.w);
    }
    __syncthreads();

    const size_t pbg = (size_t)b * NPB + pb;
    float* dst = part + pbg * (K_ * C_);
    for (int k = 0; k < K_; ++k)
        dst[k * C_ + tid] = lsum[k * 257 + tid];
    if (tid < K_) pcnt[pbg * K_ + tid] = lcnt[tid];
}

// ---------------- K1b: reduce partials -> means ----------------
__global__ __launch_bounds__(256) void k_reduce(const float* __restrict__ part,
                                                const float* __restrict__ pcnt,
                                                float* __restrict__ means) {
    const int bk = blockIdx.x;
    const int b = bk >> 6, k = bk & 63;
    const int c = threadIdx.x;
    __shared__ float cnt_s;

    if (c < NPB) {
        float cl = pcnt[((size_t)b * NPB + c) * K_ + k];
        #pragma unroll
        for (int off = NPB / 2; off; off >>= 1) cl += __shfl_down(cl, off);
        if (c == 0) cnt_s = cl;
    }
    __syncthreads();
    const float cnt = cnt_s;
    const float denom = cnt + (cnt == 0.f ? 1.f : 0.f);

    float acc = 0.f;
    #pragma unroll
    for (int pb = 0; pb < NPB; ++pb)
        acc += part[(((size_t)b * NPB + pb) * K_ + k) * C_ + c];
    means[(size_t)bk * C_ + c] = acc / denom;
}

// ---------------- K2: M=W·Wt + cwT + convw bf16 hi/lo split --------------
__global__ __launch_bounds__(256) void k_prep(const float* __restrict__ Wm,
                                              const float* __restrict__ convw,
                                              float* __restrict__ Mm,
                                              float* __restrict__ cwT,
                                              unsigned short* __restrict__ cwH,
                                              unsigned short* __restrict__ cwL) {
    const int bx = blockIdx.x, t = threadIdx.x;
    __shared__ float wl[C_];
    if (bx < C_) {
        int cr = bx;
        wl[t] = Wm[cr * C_ + t];
        __syncthreads();
        float acc = 0.f;
        for (int e = 0; e < C_; ++e) acc += wl[e] * Wm[t * C_ + e];
        Mm[cr * C_ + t] = acc;
    } else if (bx < 2 * C_) {
        int cr = bx - C_;
        cwT[cr * C_ + t] = convw[t * C_ + cr];
    } else {
        int o = bx - 2 * C_;
        float v = convw[o * C_ + t];
        unsigned h = f2bf(v);
        cwH[o * C_ + t] = (unsigned short)h;
        cwL[o * C_ + t] = (unsigned short)f2bf(v - bf2f(h));
    }
}

// ---------------- K3: P[b,i,:] = means[b,i,:] @ M ----------------
__global__ __launch_bounds__(256) void k_P(const float* __restrict__ means,
                                           const float* __restrict__ Mm,
                                           float* __restrict__ P) {
    const int bi = blockIdx.x;
    const int d = threadIdx.x;
    __shared__ float ml[C_];
    ml[d] = means[(size_t)bi * C_ + d];
    __syncthreads();
    float acc = 0.f;
    for (int cc = 0; cc < C_; ++cc) acc += ml[cc] * Mm[cc * C_ + d];
    P[(size_t)bi * C_ + d] = acc;
}

// ---------------- K4: quad[b,i,j] = (P_i-P_j).(m_i-m_j) ----------------
__global__ __launch_bounds__(256) void k_G(const float* __restrict__ P,
                                           const float* __restrict__ means,
                                           float* __restrict__ G) {
    const int bi = blockIdx.x;
    const int b = bi >> 6;
    const int t = threadIdx.x;
    __shared__ float pl[C_], ml[C_];
    pl[t] = P[(size_t)bi * C_ + t];
    ml[t] = means[(size_t)bi * C_ + t];
    __syncthreads();
    const int j = t >> 2, q = t & 3;
    const float* Pj = P + ((size_t)b * K_ + j) * C_ + q * 64;
    const float* mj = means + ((size_t)b * K_ + j) * C_ + q * 64;
    const float* pq = pl + q * 64;
    const float* mq = ml + q * 64;
    float acc = 0.f;
    for (int d0 = 0; d0 < 64; ++d0) {
        int d = (d0 + q * 16) & 63;
        acc += (pq[d] - Pj[d]) * (mq[d] - mj[d]);
    }
    acc += __shfl_xor(acc, 1);
    acc += __shfl_xor(acc, 2);
    if (q == 0) G[(size_t)bi * K_ + j] = acc;
}

// ---------------- K5: adj row + agg[b,i,:] = adj[i,:] @ means[b] ----------
__global__ __launch_bounds__(256) void k_agg(const float* __restrict__ G,
                                             const float* __restrict__ means,
                                             float* __restrict__ agg) {
    const int bi = blockIdx.x;
    const int b = bi >> 6, i = bi & 63;
    const int t = threadIdx.x;
    __shared__ float adjl[K_];
    if (t < K_) {
        int j = t;
        float quad = G[(size_t)bi * K_ + j];
        adjl[j] = (j == i) ? 0.f : expf(-quad);
    }
    __syncthreads();
    float acc = 0.f;
    for (int j = 0; j < K_; ++j)
        acc += adjl[j] * means[((size_t)b * K_ + j) * C_ + t];
    agg[(size_t)bi * C_ + t] = acc;
}

// ---------------- K6: proj[b,k,:] = agg[b,k,:] @ convwT ----------------
__global__ __launch_bounds__(256) void k_proj(const float* __restrict__ agg,
                                              const float* __restrict__ cwT,
                                              float* __restrict__ proj) {
    const int bk = blockIdx.x;
    const int o = threadIdx.x;
    __shared__ float al[C_];
    al[o] = agg[(size_t)bk * C_ + o];
    __syncthreads();
    float acc = 0.f;
    for (int cc = 0; cc < C_; ++cc) acc += al[cc] * cwT[cc * C_ + o];
    proj[(size_t)bk * C_ + o] = acc;
}

// ---------------- K7: out = convw (x) x + proj gather  [bf16-split MFMA] --
// 128x128x32 tile, 4 waves 2x2, wave = 64x64 via 4x4 16x16x32 MFMAs.
// A staged as pure bf16 copy from precomputed cwH/cwL; B loaded directly
// from x in fragment orientation (coalesced 256B runs), converted in regs,
// one b128 LDS write. One barrier pair per K-tile. LDS 40KB -> 4 blocks/CU.
#define BM 128
#define BN 128
#define BKK 32
#define STRD 80

__global__ __launch_bounds__(256) void k_gemm(const float* __restrict__ x,
                                              const int* __restrict__ idx,
                                              const unsigned short* __restrict__ cwH,
                                              const unsigned short* __restrict__ cwL,
                                              const float* __restrict__ proj,
                                              float* __restrict__ out) {
    __shared__ __align__(16) unsigned char AsH[BM * STRD]; // 10 KB each
    __shared__ __align__(16) unsigned char AsL[BM * STRD];
    __shared__ __align__(16) unsigned char BsH[BN * STRD];
    __shared__ __align__(16) unsigned char BsL[BN * STRD];

    const int tid = threadIdx.x;
    const int o0 = blockIdx.x * BM;
    const int p0 = blockIdx.y * BN;
    const int b  = blockIdx.z;

    const int lane = tid & 63;
    const int wv = tid >> 6;
    const int wo = (wv >> 1) * 64, wp = (wv & 1) * 64;
    const int lr = lane & 15, lg = lane >> 4;

    f32x4 acc[4][4];
    #pragma unroll
    for (int i = 0; i < 4; ++i)
        #pragma unroll
        for (int j = 0; j < 4; ++j) acc[i][j] = (f32x4){0.f, 0.f, 0.f, 0.f};

    const float* xb = x + (size_t)b * C_ * HW_ + p0;

    for (int kt = 0; kt < C_; kt += BKK) {
        // ---- A: pure copy of cwH/cwL tile (128 rows x 32 c) ----
        #pragma unroll
        for (int it = 0; it < 2; ++it) {
            int id = tid + it * 256;          // 0..511
            int row = id >> 2, s = id & 3;
            uint4 hv = *(const uint4*)&cwH[(o0 + row) * C_ + kt + s * 8];
            uint4 lv = *(const uint4*)&cwL[(o0 + row) * C_ + kt + s * 8];
            *(uint4*)&AsH[row * STRD + s * 16] = hv;
            *(uint4*)&AsL[row * STRD + s * 16] = lv;
        }
        // ---- B: direct fragment-oriented loads of x, convert, write ----
        #pragma unroll
        for (int it = 0; it < 2; ++it) {
            int id = tid + it * 256;          // 0..511
            int p = id & 127, cg = id >> 7;   // cg 0..3, c = cg*8 + j
            const float* xc = xb + (size_t)(kt + cg * 8) * HW_ + p;
            unsigned hh[8], ll[8];
            #pragma unroll
            for (int j = 0; j < 8; ++j) {
                float v = xc[(size_t)j * HW_];
                unsigned h = f2bf(v);
                hh[j] = h;
                ll[j] = f2bf(v - bf2f(h));
            }
            uint4 hv, lv;
            hv.x = hh[0] | (hh[1] << 16); hv.y = hh[2] | (hh[3] << 16);
            hv.z = hh[4] | (hh[5] << 16); hv.w = hh[6] | (hh[7] << 16);
            lv.x = ll[0] | (ll[1] << 16); lv.y = ll[2] | (ll[3] << 16);
            lv.z = ll[4] | (ll[5] << 16); lv.w = ll[6] | (ll[7] << 16);
            *(uint4*)&BsH[p * STRD + cg * 16] = hv;
            *(uint4*)&BsL[p * STRD + cg * 16] = lv;
        }
        __syncthreads();
        // ---- compute: 16 b128 frag reads + 48 MFMA per wave ----
        bf16x8 ah[4], al[4];
        #pragma unroll
        for (int mt = 0; mt < 4; ++mt) {
            int off = (wo + mt * 16 + lr) * STRD + lg * 16;
            ah[mt] = *(const bf16x8*)&AsH[off];
            al[mt] = *(const bf16x8*)&AsL[off];
        }
        #pragma unroll
        for (int nt = 0; nt < 4; ++nt) {
            int off = (wp + nt * 16 + lr) * STRD + lg * 16;
            bf16x8 bh = *(const bf16x8*)&BsH[off];
            bf16x8 bl = *(const bf16x8*)&BsL[off];
            #pragma unroll
            for (int mt = 0; mt < 4; ++mt) {
                acc[mt][nt] = __builtin_amdgcn_mfma_f32_16x16x32_bf16(ah[mt], bh, acc[mt][nt], 0, 0, 0);
                acc[mt][nt] = __builtin_amdgcn_mfma_f32_16x16x32_bf16(ah[mt], bl, acc[mt][nt], 0, 0, 0);
                acc[mt][nt] = __builtin_amdgcn_mfma_f32_16x16x32_bf16(al[mt], bh, acc[mt][nt], 0, 0, 0);
            }
        }
        __syncthreads();
    }

    // ---- epilogue: D[o][p] += proj[b][idx[p]][o] ----
    #pragma unroll
    for (int nt = 0; nt < 4; ++nt) {
        const int p = p0 + wp + nt * 16 + lr;
        const int kp = idx[b * HW_ + p];
        const float* pr = proj + ((size_t)b * K_ + kp) * C_;
        #pragma unroll
        for (int mt = 0; mt < 4; ++mt) {
            const int ob = o0 + wo + mt * 16 + lg * 4;
            #pragma unroll
            for (int r = 0; r < 4; ++r) {
                const int o = ob + r;
                out[((size_t)b * C_ + o) * HW_ + p] = acc[mt][nt][r] + pr[o];
            }
        }
    }
}

// ---------------- host ----------------
extern "C" void kernel_launch(void* const* d_in, const int* in_sizes, int n_in,
                              void* d_out, int out_size, void* d_ws, size_t ws_size,
                              hipStream_t stream) {
    const float* x     = (const float*)d_in[0];
    const int*   idx   = (const int*)d_in[1];
    const float* Wm    = (const float*)d_in[2];
    const float* convw = (const float*)d_in[3];
    float* out = (float*)d_out;
    float* wsf = (float*)d_ws;

    const size_t N_PART = (size_t)B_ * NPB * K_ * C_;  // 2097152 (8 MB)
    const size_t N_PCNT = (size_t)B_ * NPB * K_;       // 8192
    const size_t N_MEAN = (size_t)B_ * K_ * C_;        // 131072
    const size_t N_M    = (size_t)C_ * C_;             // 65536
    const size_t N_G    = (size_t)B_ * K_ * K_;        // 32768
    const size_t outN   = (size_t)B_ * C_ * HW_;       // 33554432

    // persistent (read during k_gemm): proj, cwT, cwH, cwL -> ws head
    float* proj = wsf;                                   // 131072 f
    float* cwT  = wsf + N_MEAN;                          // 65536 f
    unsigned short* cwH = (unsigned short*)(wsf + N_MEAN + N_M);       // 65536 u16
    unsigned short* cwL = cwH + N_M;                                   // 65536 u16
    const size_t wsHeadF = N_MEAN + N_M + N_M;           // cwH+cwL = N_M floats

    const size_t earlyN = N_PART + N_PCNT + N_MEAN + N_M + N_MEAN + N_G + N_MEAN;
    const size_t needAll = (wsHeadF + earlyN) * sizeof(float);
    float* early = (ws_size >= needAll) ? (wsf + wsHeadF)
                                        : (out + (outN - earlyN));

    float* part  = early;
    float* pcnt  = part + N_PART;
    float* means = pcnt + N_PCNT;
    float* Mm    = means + N_MEAN;
    float* P     = Mm + N_M;
    float* G     = P + N_MEAN;
    float* agg   = G + N_G;

    k_scatter<<<dim3(NPB, B_), dim3(256), 0, stream>>>(x, idx, part, pcnt);
    k_reduce<<<dim3(512), dim3(256), 0, stream>>>(part, pcnt, means);
    k_prep<<<dim3(768), dim3(256), 0, stream>>>(Wm, convw, Mm, cwT, cwH, cwL);
    k_P<<<dim3(512), dim3(256), 0, stream>>>(means, Mm, P);
    k_G<<<dim3(512), dim3(256), 0, stream>>>(P, means, G);
    k_agg<<<dim3(512), dim3(256), 0, stream>>>(G, means, agg);
    k_proj<<<dim3(512), dim3(256), 0, stream>>>(agg, cwT, proj);
    k_gemm<<<dim3(2, HW_ / BN, B_), dim3(256), 0, stream>>>(x, idx, cwH, cwL, proj, out);
}

// Round 9
// 503.368 us; speedup vs baseline: 1.3285x; 1.3285x over previous
//
#include <hip/hip_runtime.h>
#include <cstdint>
#include <cstddef>

#define B_  8
#define C_  256
#define HW_ 16384
#define K_  64
#define PPB 1024          // pixels per scatter block
#define NPB (HW_ / PPB)   // 16 pixel-blocks per batch
#define CS  32            // channel slice per scatter block
#define NCB (C_ / CS)     // 8 channel-blocks

typedef __attribute__((ext_vector_type(8))) short bf16x8;
typedef __attribute__((ext_vector_type(4))) float f32x4;

__device__ __forceinline__ unsigned f2bf(float f) {
    unsigned u = __builtin_bit_cast(unsigned, f);
    return (u + 0x7FFFu + ((u >> 16) & 1u)) >> 16;
}
__device__ __forceinline__ float bf2f(unsigned h) {
    unsigned u = h << 16;
    return __builtin_bit_cast(float, u);
}

// ---------------- K1: segment scatter-sum -> per-block partials ----------
// grid (16 pb, 8 cb, 8 b) = 1024 blocks (4/CU, ~16 waves/CU). Each block:
// 1024 pixels x 32 channels. lane = pixel (float4/thread -> 1KB/wave
// coalesced loads), cluster ids in registers, fire-and-forget ds_add_f32
// into lsum[k*33+c] -> bank (k+c)%32, ~2-way on random k (free, m136).
__global__ __launch_bounds__(256, 4) void k_scatter(const float* __restrict__ x,
                                                    const int* __restrict__ idx,
                                                    float* __restrict__ part,
                                                    float* __restrict__ pcnt) {
    __shared__ float lsum[K_ * (CS + 1)];   // 8448 B
    __shared__ float lcnt[K_];
    const int tid = threadIdx.x;
    const int pb = blockIdx.x;
    const int cb = blockIdx.y;
    const int b  = blockIdx.z;
    const int p0 = pb * PPB;
    const int c0 = cb * CS;

    for (int i = tid; i < K_ * (CS + 1); i += 256) lsum[i] = 0.f;
    if (tid < K_) lcnt[tid] = 0.f;
    __syncthreads();

    const int p = p0 + tid * 4;
    const int4 kv = *(const int4*)(idx + b * HW_ + p);
    if (cb == 0) {
        atomicAdd(&lcnt[kv.x], 1.f);
        atomicAdd(&lcnt[kv.y], 1.f);
        atomicAdd(&lcnt[kv.z], 1.f);
        atomicAdd(&lcnt[kv.w], 1.f);
    }

    float* a0 = &lsum[kv.x * (CS + 1)];
    float* a1 = &lsum[kv.y * (CS + 1)];
    float* a2 = &lsum[kv.z * (CS + 1)];
    float* a3 = &lsum[kv.w * (CS + 1)];
    const float* xp = x + ((size_t)b * C_ + c0) * HW_ + p;
    #pragma unroll 8
    for (int c = 0; c < CS; ++c) {
        float4 v = *(const float4*)(xp + (size_t)c * HW_);
        atomicAdd(a0 + c, v.x);
        atomicAdd(a1 + c, v.y);
        atomicAdd(a2 + c, v.z);
        atomicAdd(a3 + c, v.w);
    }
    __syncthreads();

    const size_t pbg = (size_t)b * NPB + pb;
    float* dst = part + pbg * (K_ * C_) + c0;
    for (int i = tid; i < K_ * CS; i += 256) {
        int k = i >> 5, c = i & (CS - 1);
        dst[k * C_ + c] = lsum[k * (CS + 1) + c];
    }
    if (cb == 0 && tid < K_) pcnt[pbg * K_ + tid] = lcnt[tid];
}

// ---------------- K1b: reduce partials -> means ----------------
__global__ __launch_bounds__(256) void k_reduce(const float* __restrict__ part,
                                                const float* __restrict__ pcnt,
                                                float* __restrict__ means) {
    const int bk = blockIdx.x;
    const int b = bk >> 6, k = bk & 63;
    const int c = threadIdx.x;
    __shared__ float cnt_s;

    if (c < NPB) {
        float cl = pcnt[((size_t)b * NPB + c) * K_ + k];
        #pragma unroll
        for (int off = NPB / 2; off; off >>= 1) cl += __shfl_down(cl, off);
        if (c == 0) cnt_s = cl;
    }
    __syncthreads();
    const float cnt = cnt_s;
    const float denom = cnt + (cnt == 0.f ? 1.f : 0.f);

    float acc = 0.f;
    #pragma unroll
    for (int pb = 0; pb < NPB; ++pb)
        acc += part[(((size_t)b * NPB + pb) * K_ + k) * C_ + c];
    means[(size_t)bk * C_ + c] = acc / denom;
}

// ---------------- K2: M=W·Wt + cwT + convw bf16 hi/lo split --------------
__global__ __launch_bounds__(256) void k_prep(const float* __restrict__ Wm,
                                              const float* __restrict__ convw,
                                              float* __restrict__ Mm,
                                              float* __restrict__ cwT,
                                              unsigned short* __restrict__ cwH,
                                              unsigned short* __restrict__ cwL) {
    const int bx = blockIdx.x, t = threadIdx.x;
    __shared__ float wl[C_];
    if (bx < C_) {
        int cr = bx;
        wl[t] = Wm[cr * C_ + t];
        __syncthreads();
        float acc = 0.f;
        for (int e = 0; e < C_; ++e) acc += wl[e] * Wm[t * C_ + e];
        Mm[cr * C_ + t] = acc;
    } else if (bx < 2 * C_) {
        int cr = bx - C_;
        cwT[cr * C_ + t] = convw[t * C_ + cr];
    } else {
        int o = bx - 2 * C_;
        float v = convw[o * C_ + t];
        unsigned h = f2bf(v);
        cwH[o * C_ + t] = (unsigned short)h;
        cwL[o * C_ + t] = (unsigned short)f2bf(v - bf2f(h));
    }
}

// ---------------- K3: P[b,i,:] = means[b,i,:] @ M ----------------
__global__ __launch_bounds__(256) void k_P(const float* __restrict__ means,
                                           const float* __restrict__ Mm,
                                           float* __restrict__ P) {
    const int bi = blockIdx.x;
    const int d = threadIdx.x;
    __shared__ float ml[C_];
    ml[d] = means[(size_t)bi * C_ + d];
    __syncthreads();
    float acc = 0.f;
    for (int cc = 0; cc < C_; ++cc) acc += ml[cc] * Mm[cc * C_ + d];
    P[(size_t)bi * C_ + d] = acc;
}

// ---------------- K4: quad[b,i,j] = (P_i-P_j).(m_i-m_j) ----------------
// Difference form: exact for symmetric M, avoids Gii+Gjj-2Gij cancellation.
__global__ __launch_bounds__(256) void k_G(const float* __restrict__ P,
                                           const float* __restrict__ means,
                                           float* __restrict__ G) {
    const int bi = blockIdx.x;
    const int b = bi >> 6;
    const int t = threadIdx.x;
    __shared__ float pl[C_], ml[C_];
    pl[t] = P[(size_t)bi * C_ + t];
    ml[t] = means[(size_t)bi * C_ + t];
    __syncthreads();
    const int j = t >> 2, q = t & 3;
    const float* Pj = P + ((size_t)b * K_ + j) * C_ + q * 64;
    const float* mj = means + ((size_t)b * K_ + j) * C_ + q * 64;
    const float* pq = pl + q * 64;
    const float* mq = ml + q * 64;
    float acc = 0.f;
    for (int d0 = 0; d0 < 64; ++d0) {
        int d = (d0 + q * 16) & 63;
        acc += (pq[d] - Pj[d]) * (mq[d] - mj[d]);
    }
    acc += __shfl_xor(acc, 1);
    acc += __shfl_xor(acc, 2);
    if (q == 0) G[(size_t)bi * K_ + j] = acc;
}

// ---------------- K5: adj row + agg[b,i,:] = adj[i,:] @ means[b] ----------
__global__ __launch_bounds__(256) void k_agg(const float* __restrict__ G,
                                             const float* __restrict__ means,
                                             float* __restrict__ agg) {
    const int bi = blockIdx.x;
    const int b = bi >> 6, i = bi & 63;
    const int t = threadIdx.x;
    __shared__ float adjl[K_];
    if (t < K_) {
        int j = t;
        float quad = G[(size_t)bi * K_ + j];
        adjl[j] = (j == i) ? 0.f : expf(-quad);
    }
    __syncthreads();
    float acc = 0.f;
    for (int j = 0; j < K_; ++j)
        acc += adjl[j] * means[((size_t)b * K_ + j) * C_ + t];
    agg[(size_t)bi * C_ + t] = acc;
}

// ---------------- K6: proj[b,k,:] = agg[b,k,:] @ convwT ----------------
__global__ __launch_bounds__(256) void k_proj(const float* __restrict__ agg,
                                              const float* __restrict__ cwT,
                                              float* __restrict__ proj) {
    const int bk = blockIdx.x;
    const int o = threadIdx.x;
    __shared__ float al[C_];
    al[o] = agg[(size_t)bk * C_ + o];
    __syncthreads();
    float acc = 0.f;
    for (int cc = 0; cc < C_; ++cc) acc += al[cc] * cwT[cc * C_ + o];
    proj[(size_t)bk * C_ + o] = acc;
}

// ---------------- K7: out = convw (x) x + proj gather  [bf16-split MFMA] --
// 128x128x32 tile, 4 waves 2x2, wave = 64x64 via 4x4 16x16x32 MFMAs.
// A staged as pure bf16 copy from precomputed cwH/cwL; B loaded directly
// from x in fragment orientation (coalesced 256B runs), converted in regs,
// one b128 LDS write. One barrier pair per K-tile. LDS 40KB -> 4 blocks/CU.
// grid (2 o-tiles fastest, 128 p-tiles, 8 b): o-tile pair shares x tile in L2.
#define BM 128
#define BN 128
#define BKK 32
#define STRD 80

__global__ __launch_bounds__(256) void k_gemm(const float* __restrict__ x,
                                              const int* __restrict__ idx,
                                              const unsigned short* __restrict__ cwH,
                                              const unsigned short* __restrict__ cwL,
                                              const float* __restrict__ proj,
                                              float* __restrict__ out) {
    __shared__ __align__(16) unsigned char AsH[BM * STRD]; // 10 KB each
    __shared__ __align__(16) unsigned char AsL[BM * STRD];
    __shared__ __align__(16) unsigned char BsH[BN * STRD];
    __shared__ __align__(16) unsigned char BsL[BN * STRD];

    const int tid = threadIdx.x;
    const int o0 = blockIdx.x * BM;
    const int p0 = blockIdx.y * BN;
    const int b  = blockIdx.z;

    const int lane = tid & 63;
    const int wv = tid >> 6;
    const int wo = (wv >> 1) * 64, wp = (wv & 1) * 64;
    const int lr = lane & 15, lg = lane >> 4;

    f32x4 acc[4][4];
    #pragma unroll
    for (int i = 0; i < 4; ++i)
        #pragma unroll
        for (int j = 0; j < 4; ++j) acc[i][j] = (f32x4){0.f, 0.f, 0.f, 0.f};

    const float* xb = x + (size_t)b * C_ * HW_ + p0;

    for (int kt = 0; kt < C_; kt += BKK) {
        // ---- A: pure copy of cwH/cwL tile (128 rows x 32 c) ----
        #pragma unroll
        for (int it = 0; it < 2; ++it) {
            int id = tid + it * 256;          // 0..511
            int row = id >> 2, s = id & 3;
            uint4 hv = *(const uint4*)&cwH[(o0 + row) * C_ + kt + s * 8];
            uint4 lv = *(const uint4*)&cwL[(o0 + row) * C_ + kt + s * 8];
            *(uint4*)&AsH[row * STRD + s * 16] = hv;
            *(uint4*)&AsL[row * STRD + s * 16] = lv;
        }
        // ---- B: direct fragment-oriented loads of x, convert, write ----
        #pragma unroll
        for (int it = 0; it < 2; ++it) {
            int id = tid + it * 256;          // 0..511
            int p = id & 127, cg = id >> 7;   // cg 0..3, c = cg*8 + j
            const float* xc = xb + (size_t)(kt + cg * 8) * HW_ + p;
            unsigned hh[8], ll[8];
            #pragma unroll
            for (int j = 0; j < 8; ++j) {
                float v = xc[(size_t)j * HW_];
                unsigned h = f2bf(v);
                hh[j] = h;
                ll[j] = f2bf(v - bf2f(h));
            }
            uint4 hv, lv;
            hv.x = hh[0] | (hh[1] << 16); hv.y = hh[2] | (hh[3] << 16);
            hv.z = hh[4] | (hh[5] << 16); hv.w = hh[6] | (hh[7] << 16);
            lv.x = ll[0] | (ll[1] << 16); lv.y = ll[2] | (ll[3] << 16);
            lv.z = ll[4] | (ll[5] << 16); lv.w = ll[6] | (ll[7] << 16);
            *(uint4*)&BsH[p * STRD + cg * 16] = hv;
            *(uint4*)&BsL[p * STRD + cg * 16] = lv;
        }
        __syncthreads();
        // ---- compute: 16 b128 frag reads + 48 MFMA per wave ----
        bf16x8 ah[4], al[4];
        #pragma unroll
        for (int mt = 0; mt < 4; ++mt) {
            int off = (wo + mt * 16 + lr) * STRD + lg * 16;
            ah[mt] = *(const bf16x8*)&AsH[off];
            al[mt] = *(const bf16x8*)&AsL[off];
        }
        #pragma unroll
        for (int nt = 0; nt < 4; ++nt) {
            int off = (wp + nt * 16 + lr) * STRD + lg * 16;
            bf16x8 bh = *(const bf16x8*)&BsH[off];
            bf16x8 bl = *(const bf16x8*)&BsL[off];
            #pragma unroll
            for (int mt = 0; mt < 4; ++mt) {
                acc[mt][nt] = __builtin_amdgcn_mfma_f32_16x16x32_bf16(ah[mt], bh, acc[mt][nt], 0, 0, 0);
                acc[mt][nt] = __builtin_amdgcn_mfma_f32_16x16x32_bf16(ah[mt], bl, acc[mt][nt], 0, 0, 0);
                acc[mt][nt] = __builtin_amdgcn_mfma_f32_16x16x32_bf16(al[mt], bh, acc[mt][nt], 0, 0, 0);
            }
        }
        __syncthreads();
    }

    // ---- epilogue: D[o][p] += proj[b][idx[p]][o] ----
    #pragma unroll
    for (int nt = 0; nt < 4; ++nt) {
        const int p = p0 + wp + nt * 16 + lr;
        const int kp = idx[b * HW_ + p];
        const float* pr = proj + ((size_t)b * K_ + kp) * C_;
        #pragma unroll
        for (int mt = 0; mt < 4; ++mt) {
            const int ob = o0 + wo + mt * 16 + lg * 4;
            #pragma unroll
            for (int r = 0; r < 4; ++r) {
                const int o = ob + r;
                out[((size_t)b * C_ + o) * HW_ + p] = acc[mt][nt][r] + pr[o];
            }
        }
    }
}

// ---------------- host ----------------
extern "C" void kernel_launch(void* const* d_in, const int* in_sizes, int n_in,
                              void* d_out, int out_size, void* d_ws, size_t ws_size,
                              hipStream_t stream) {
    const float* x     = (const float*)d_in[0];
    const int*   idx   = (const int*)d_in[1];
    const float* Wm    = (const float*)d_in[2];
    const float* convw = (const float*)d_in[3];
    float* out = (float*)d_out;
    float* wsf = (float*)d_ws;

    const size_t N_PART = (size_t)B_ * NPB * K_ * C_;  // 2097152 (8 MB)
    const size_t N_PCNT = (size_t)B_ * NPB * K_;       // 8192
    const size_t N_MEAN = (size_t)B_ * K_ * C_;        // 131072
    const size_t N_M    = (size_t)C_ * C_;             // 65536
    const size_t N_G    = (size_t)B_ * K_ * K_;        // 32768
    const size_t outN   = (size_t)B_ * C_ * HW_;       // 33554432

    // persistent (read during k_gemm): proj, cwT, cwH, cwL -> ws head (1 MB)
    float* proj = wsf;                                   // 131072 f
    float* cwT  = wsf + N_MEAN;                          // 65536 f
    unsigned short* cwH = (unsigned short*)(wsf + N_MEAN + N_M);       // 65536 u16
    unsigned short* cwL = cwH + N_M;                                   // 65536 u16
    const size_t wsHeadF = N_MEAN + N_M + N_M;           // cwH+cwL = N_M floats

    const size_t earlyN = N_PART + N_PCNT + N_MEAN + N_M + N_MEAN + N_G + N_MEAN;
    const size_t needAll = (wsHeadF + earlyN) * sizeof(float);
    float* early = (ws_size >= needAll) ? (wsf + wsHeadF)
                                        : (out + (outN - earlyN));

    float* part  = early;
    float* pcnt  = part + N_PART;
    float* means = pcnt + N_PCNT;
    float* Mm    = means + N_MEAN;
    float* P     = Mm + N_M;
    float* G     = P + N_MEAN;
    float* agg   = G + N_G;

    k_scatter<<<dim3(NPB, NCB, B_), dim3(256), 0, stream>>>(x, idx, part, pcnt);
    k_reduce<<<dim3(512), dim3(256), 0, stream>>>(part, pcnt, means);
    k_prep<<<dim3(768), dim3(256), 0, stream>>>(Wm, convw, Mm, cwT, cwH, cwL);
    k_P<<<dim3(512), dim3(256), 0, stream>>>(means, Mm, P);
    k_G<<<dim3(512), dim3(256), 0, stream>>>(P, means, G);
    k_agg<<<dim3(512), dim3(256), 0, stream>>>(G, means, agg);
    k_proj<<<dim3(512), dim3(256), 0, stream>>>(agg, cwT, proj);
    k_gemm<<<dim3(2, HW_ / BN, B_), dim3(256), 0, stream>>>(x, idx, cwH, cwL, proj, out);
}